// Round 2
// baseline (171.170 us; speedup 1.0000x reference)
//
#include <hip/hip_runtime.h>
#include <math.h>

// LightconvLayer: x (T,B,C) f32, weight (H,K) f32 -> out (T,B,C) f32
// out[t,b,c] = sum_k softmax(weight[c/(C/H)])[k] * x[t+k-PAD_L, b, c] (zero-pad left)
#define T_LEN 2048
#define B_SZ  8
#define C_SZ  1024
#define NH    16
#define KW    31
#define PADL  30
#define TT    16      // output rows per block along t
#define BLOCK 256     // 256 threads x float4 = all 1024 channels

__global__ __launch_bounds__(BLOCK, 4) void lightconv_kernel(
    const float* __restrict__ x, const float* __restrict__ weight,
    float* __restrict__ out) {
  __shared__ float sw[NH][KW];
  const int tid = threadIdx.x;

  // --- softmax(weight) into LDS: 16 threads, one head each ---
  if (tid < NH) {
    float wv[KW];
    float m = -1e30f;
#pragma unroll
    for (int k = 0; k < KW; ++k) {
      wv[k] = weight[tid * KW + k];
      m = fmaxf(m, wv[k]);
    }
    float s = 0.f;
#pragma unroll
    for (int k = 0; k < KW; ++k) {
      wv[k] = expf(wv[k] - m);
      s += wv[k];
    }
    const float inv = 1.f / s;
#pragma unroll
    for (int k = 0; k < KW; ++k) sw[tid][k] = wv[k] * inv;
  }
  __syncthreads();

  // thread -> 4 consecutive channels (float4); head = (4*tid)/64 = tid>>4
  // (a float4 never crosses a head boundary: 64/4 = 16 groups per head)
  const int head = tid >> 4;
  float wk[KW];
#pragma unroll
  for (int k = 0; k < KW; ++k) wk[k] = sw[head][k];

  const int b  = blockIdx.y;
  const int t0 = blockIdx.x * TT;

  const int R4 = B_SZ * C_SZ / 4;  // float4 stride between t rows = 2048
  const float4* xp = (const float4*)x + (size_t)b * (C_SZ / 4) + tid;

  float4 acc[TT];
#pragma unroll
  for (int o = 0; o < TT; ++o) acc[o] = make_float4(0.f, 0.f, 0.f, 0.f);

  // stream input rows i = 0..TT+KW-2  (t = t0 + i - PADL)
#pragma unroll
  for (int i = 0; i < TT + KW - 1; ++i) {
    const int t = t0 + i - PADL;  // block-uniform sign; t <= t0+TT-1 <= T-1 always
    float4 xv;
    if (t >= 0) {
      xv = xp[(size_t)t * R4];
    } else {
      xv = make_float4(0.f, 0.f, 0.f, 0.f);
    }
    const int olo = (i - (KW - 1) > 0) ? i - (KW - 1) : 0;
    const int ohi = (i < TT - 1) ? i : TT - 1;
#pragma unroll
    for (int o = olo; o <= ohi; ++o) {
      const float w = wk[i - o];
      acc[o].x = fmaf(w, xv.x, acc[o].x);
      acc[o].y = fmaf(w, xv.y, acc[o].y);
      acc[o].z = fmaf(w, xv.z, acc[o].z);
      acc[o].w = fmaf(w, xv.w, acc[o].w);
    }
  }

  float4* op = (float4*)out + ((size_t)t0 * B_SZ + b) * (C_SZ / 4) + tid;
#pragma unroll
  for (int o = 0; o < TT; ++o) {
    op[(size_t)o * R4] = acc[o];
  }
}

extern "C" void kernel_launch(void* const* d_in, const int* in_sizes, int n_in,
                              void* d_out, int out_size, void* d_ws, size_t ws_size,
                              hipStream_t stream) {
  const float* x = (const float*)d_in[0];      // (T,B,C) f32
  const float* w = (const float*)d_in[1];      // (H,K) f32
  float* out = (float*)d_out;                  // (T,B,C) f32
  (void)in_sizes; (void)n_in; (void)out_size; (void)d_ws; (void)ws_size;

  dim3 grid(T_LEN / TT, B_SZ);                 // (128, 8) = 1024 blocks
  dim3 block(BLOCK);
  lightconv_kernel<<<grid, block, 0, stream>>>(x, w, out);
}

// Round 3
// 132.763 us; speedup vs baseline: 1.2893x; 1.2893x over previous
//
#include <hip/hip_runtime.h>
#include <math.h>

// LightconvLayer: x (T,B,C) f32, weight (H,K) f32 -> out (T,B,C) f32
// out[t,b,c] = sum_k softmax(weight[c/(C/H)])[k] * x[t+k-PAD_L, b, c] (zero-pad left)
#define T_LEN 2048
#define B_SZ  8
#define C_SZ  1024
#define NH    16
#define KW    31
#define PADL  30
#define TT    16      // output rows per block along t
#define BLOCK 256     // 256 threads x float4 = all 1024 channels

__global__ __launch_bounds__(BLOCK, 4) void lightconv_kernel(
    const float* __restrict__ x, const float* __restrict__ weight,
    float* __restrict__ out) {
  __shared__ float sw[NH][KW];
  const int tid = threadIdx.x;

  // --- softmax(weight) into LDS: 16 threads, one head each ---
  if (tid < NH) {
    float wv[KW];
    float m = -1e30f;
#pragma unroll
    for (int k = 0; k < KW; ++k) {
      wv[k] = weight[tid * KW + k];
      m = fmaxf(m, wv[k]);
    }
    float s = 0.f;
#pragma unroll
    for (int k = 0; k < KW; ++k) {
      wv[k] = expf(wv[k] - m);
      s += wv[k];
    }
    const float inv = 1.f / s;
#pragma unroll
    for (int k = 0; k < KW; ++k) sw[tid][k] = wv[k] * inv;
  }
  __syncthreads();

  // thread -> 4 consecutive channels (float4); head = (4*tid)/64 = tid>>4
  const int head = tid >> 4;
  float wk[KW];
#pragma unroll
  for (int k = 0; k < KW; ++k) wk[k] = sw[head][k];

  const int b  = blockIdx.y;
  const int t0 = blockIdx.x * TT;

  const int R4 = B_SZ * C_SZ / 4;  // float4 stride between t rows = 2048
  const float4* xp = (const float4*)x + (size_t)b * (C_SZ / 4) + tid;

  float4 acc[TT];
#pragma unroll
  for (int o = 0; o < TT; ++o) acc[o] = make_float4(0.f, 0.f, 0.f, 0.f);

  // stream input rows i = 0..TT+KW-2  (t = t0 + i - PADL)
  // ALL loop bounds and array indices are compile-time constants (rule #20):
  // the guard below constant-folds per unrolled (i,o) pair.
#pragma unroll
  for (int i = 0; i < TT + KW - 1; ++i) {
    const int t = t0 + i - PADL;  // only first t-strip clips; block-uniform sign
    float4 xv;
    if (t >= 0) {
      xv = xp[(size_t)t * R4];
    } else {
      xv = make_float4(0.f, 0.f, 0.f, 0.f);
    }
#pragma unroll
    for (int o = 0; o < TT; ++o) {
      const int k = i - o;               // compile-time constant
      if (k >= 0 && k < KW) {            // constant-folds away
        const float w = wk[k];
        acc[o].x = fmaf(w, xv.x, acc[o].x);
        acc[o].y = fmaf(w, xv.y, acc[o].y);
        acc[o].z = fmaf(w, xv.z, acc[o].z);
        acc[o].w = fmaf(w, xv.w, acc[o].w);
      }
    }
  }

  float4* op = (float4*)out + ((size_t)t0 * B_SZ + b) * (C_SZ / 4) + tid;
#pragma unroll
  for (int o = 0; o < TT; ++o) {
    op[(size_t)o * R4] = acc[o];
  }
}

extern "C" void kernel_launch(void* const* d_in, const int* in_sizes, int n_in,
                              void* d_out, int out_size, void* d_ws, size_t ws_size,
                              hipStream_t stream) {
  const float* x = (const float*)d_in[0];      // (T,B,C) f32
  const float* w = (const float*)d_in[1];      // (H,K) f32
  float* out = (float*)d_out;                  // (T,B,C) f32
  (void)in_sizes; (void)n_in; (void)out_size; (void)d_ws; (void)ws_size;

  dim3 grid(T_LEN / TT, B_SZ);                 // (128, 8) = 1024 blocks
  dim3 block(BLOCK);
  lightconv_kernel<<<grid, block, 0, stream>>>(x, w, out);
}

// Round 4
// 51.383 us; speedup vs baseline: 3.3312x; 2.5838x over previous
//
#include <hip/hip_runtime.h>
#include <math.h>

// LightconvLayer: x (T,B,C) f32, weight (H,K) f32 -> out (T,B,C) f32
// out[t,b,c] = sum_k softmax(weight[c/(C/H)])[k] * x[t+k-PAD_L, b, c] (zero-pad left)
#define T_LEN 2048
#define B_SZ  8
#define C_SZ  1024
#define NH    16
#define KW    31
#define PADL  30
#define TT    16      // output rows per block along t
#define BLOCK 256     // 256 threads x float4 = all 1024 channels

// __launch_bounds__(256, 2): min 2 waves/EU -> VGPR cap 256. R3 showed the
// allocator targeting 8 waves/EU (64-VGPR cap) and spilling acc[] to scratch
// (WRITE_SIZE 268MB vs 64MB of real output). Give it room; no spill possible.
template <bool CLIP>
__device__ __forceinline__ void conv_body(const float4* __restrict__ xp,
                                          float4* __restrict__ op,
                                          const float* __restrict__ wk,
                                          int t0) {
  const int R4 = B_SZ * C_SZ / 4;  // float4 stride between t rows = 2048

  float4 acc[TT];
#pragma unroll
  for (int o = 0; o < TT; ++o) acc[o] = make_float4(0.f, 0.f, 0.f, 0.f);

  // stream input rows i = 0..TT+KW-2  (t = t0 + i - PADL); all indices
  // compile-time constants -> acc/wk stay in registers (rule #20).
#pragma unroll
  for (int i = 0; i < TT + KW - 1; ++i) {
    const int t = t0 + i - PADL;
    float4 xv;
    if (CLIP) {
      xv = (t >= 0) ? xp[(size_t)t * R4] : make_float4(0.f, 0.f, 0.f, 0.f);
    } else {
      xv = xp[(size_t)t * R4];
    }
#pragma unroll
    for (int o = 0; o < TT; ++o) {
      const int k = i - o;               // compile-time constant
      if (k >= 0 && k < KW) {            // constant-folds away
        const float w = wk[k];
        acc[o].x = fmaf(w, xv.x, acc[o].x);
        acc[o].y = fmaf(w, xv.y, acc[o].y);
        acc[o].z = fmaf(w, xv.z, acc[o].z);
        acc[o].w = fmaf(w, xv.w, acc[o].w);
      }
    }
  }

#pragma unroll
  for (int o = 0; o < TT; ++o) {
    op[(size_t)o * R4] = acc[o];
  }
}

__global__ __launch_bounds__(BLOCK, 2) void lightconv_kernel(
    const float* __restrict__ x, const float* __restrict__ weight,
    float* __restrict__ out) {
  __shared__ float sw[NH][KW];
  const int tid = threadIdx.x;

  // --- softmax(weight) into LDS: 16 threads, one head each ---
  if (tid < NH) {
    float wv[KW];
    float m = -1e30f;
#pragma unroll
    for (int k = 0; k < KW; ++k) {
      wv[k] = weight[tid * KW + k];
      m = fmaxf(m, wv[k]);
    }
    float s = 0.f;
#pragma unroll
    for (int k = 0; k < KW; ++k) {
      wv[k] = expf(wv[k] - m);
      s += wv[k];
    }
    const float inv = 1.f / s;
#pragma unroll
    for (int k = 0; k < KW; ++k) sw[tid][k] = wv[k] * inv;
  }
  __syncthreads();

  // thread -> 4 consecutive channels (float4); head = (4*tid)/64 = tid>>4
  const int head = tid >> 4;
  float wk[KW];
#pragma unroll
  for (int k = 0; k < KW; ++k) wk[k] = sw[head][k];

  const int b  = blockIdx.y;
  const int t0 = blockIdx.x * TT;

  const float4* xp = (const float4*)x + (size_t)b * (C_SZ / 4) + tid;
  float4* op = (float4*)out + ((size_t)t0 * B_SZ + b) * (C_SZ / 4) + tid;

  // Only blockIdx.x in {0,1} can see t < 0 (t0 - PADL < 0 iff t0 < 30).
  if (t0 >= PADL) {
    conv_body<false>(xp, op, wk, t0);
  } else {
    conv_body<true>(xp, op, wk, t0);
  }
}

extern "C" void kernel_launch(void* const* d_in, const int* in_sizes, int n_in,
                              void* d_out, int out_size, void* d_ws, size_t ws_size,
                              hipStream_t stream) {
  const float* x = (const float*)d_in[0];      // (T,B,C) f32
  const float* w = (const float*)d_in[1];      // (H,K) f32
  float* out = (float*)d_out;                  // (T,B,C) f32
  (void)in_sizes; (void)n_in; (void)out_size; (void)d_ws; (void)ws_size;

  dim3 grid(T_LEN / TT, B_SZ);                 // (128, 8) = 1024 blocks
  dim3 block(BLOCK);
  lightconv_kernel<<<grid, block, 0, stream>>>(x, w, out);
}